// Round 5
// baseline (646.918 us; speedup 1.0000x reference)
//
#include <hip/hip_runtime.h>
#include <stdint.h>

#define N_NODES 100000
#define N_EDGES 400000
#define N_GRAPHS 2000
#define C_IN 48
#define HD 128
#define NLAYERS 6
#define BN_EPS 1e-5f
#define NSLOPE 0.01f
#define SB 391   // ceil(N_NODES/256)
#define NREP 8   // stats replication factor
#define ECAP 512 // edge window per block (block edges ~ Poisson(128); P(>512) ~ 0)
#define SLICE 8192          // source-node slice: 8192 rows * 256 B = 2 MB (< 4 MB L2/XCD)
#define NSLICES 13          // ceil(100000 / 8192)

typedef uint16_t u16;
typedef uint32_t u32;
typedef short bf16x8 __attribute__((ext_vector_type(8)));
typedef float f32x4 __attribute__((ext_vector_type(4)));

__device__ __forceinline__ float bf2f_lo(u32 v) { return __uint_as_float(v << 16); }
__device__ __forceinline__ float bf2f_hi(u32 v) { return __uint_as_float(v & 0xffff0000u); }
__device__ __forceinline__ float bf2f(u16 h) { return __uint_as_float(((u32)h) << 16); }
__device__ __forceinline__ u16 f2bf(float f) {
    u32 u = __float_as_uint(f);
    u32 r = (u + 0x7fffu + ((u >> 16) & 1u)) >> 16;
    return (u16)r;
}
__device__ __forceinline__ u32 pack2(float a, float b) {
    return (u32)f2bf(a) | ((u32)f2bf(b) << 16);
}
__device__ __forceinline__ float lrelu(float v) { return v >= 0.f ? v : v * NSLOPE; }

// register accumulate helpers
__device__ __forceinline__ void acc_bn(float* a, const uint4 v, const float* cA, const float* cB) {
    const u32 w[4] = {v.x, v.y, v.z, v.w};
    #pragma unroll
    for (int p = 0; p < 4; ++p) {
        a[2 * p]     += lrelu(cA[2 * p] * bf2f_lo(w[p]) + cB[2 * p]);
        a[2 * p + 1] += lrelu(cA[2 * p + 1] * bf2f_hi(w[p]) + cB[2 * p + 1]);
    }
}
__device__ __forceinline__ void acc_bf16row(float* a, const uint4 v) {
    const u32 w[4] = {v.x, v.y, v.z, v.w};
    #pragma unroll
    for (int p = 0; p < 4; ++p) {
        a[2 * p]     += bf2f_lo(w[p]);
        a[2 * p + 1] += bf2f_hi(w[p]);
    }
}
__device__ __forceinline__ void acc_f32row(float* a, const float* p) {
    const float4 u0 = reinterpret_cast<const float4*>(p)[0];
    const float4 u1 = reinterpret_cast<const float4*>(p)[1];
    a[0] += u0.x; a[1] += u0.y; a[2] += u0.z; a[3] += u0.w;
    a[4] += u1.x; a[5] += u1.y; a[6] += u1.z; a[7] += u1.w;
}
__device__ __forceinline__ void ld_xrow(float* a, const void* xv, int md, int idx, int seg) {
    if (md) acc_f32row(a, (const float*)xv + (size_t)idx * C_IN + seg * 8);
    else    acc_bf16row(a, *reinterpret_cast<const uint4*>((const u16*)xv + (size_t)idx * C_IN + seg * 8));
}

// dtype detection: mode=1 -> float inputs are fp32; mode=0 -> bf16.
__global__ __launch_bounds__(256) void detect_kernel(const u16* __restrict__ x, int* __restrict__ mode) {
    __shared__ int flag;
    if (threadIdx.x == 0) flag = 0;
    __syncthreads();
    int local = 0;
    for (int i = threadIdx.x; i < 16384; i += 256) {
        float a = fabsf(bf2f(x[i]));
        if (!(a < 1e4f)) local = 1;
    }
    if (local) flag = 1;
    __syncthreads();
    if (threadIdx.x == 0) mode[0] = flag;
}

// ---------------- CSR build ----------------
__global__ __launch_bounds__(256) void hist_kernel(const int* __restrict__ dst, int* __restrict__ cnt) {
    int e = blockIdx.x * 256 + threadIdx.x;
    if (e < N_EDGES) atomicAdd(&cnt[dst[e]], 1);
}

__global__ __launch_bounds__(256) void scan1_kernel(const int* __restrict__ cnt, int* __restrict__ bsum) {
    __shared__ int s[256];
    const int t = threadIdx.x;
    const int i = blockIdx.x * 256 + t;
    s[t] = (i < N_NODES) ? cnt[i] : 0;
    __syncthreads();
    for (int d = 128; d > 0; d >>= 1) {
        if (t < d) s[t] += s[t + d];
        __syncthreads();
    }
    if (t == 0) bsum[blockIdx.x] = s[0];
}

__global__ __launch_bounds__(512) void scan2_kernel(int* __restrict__ bsum, int* __restrict__ row_ptr) {
    __shared__ int s[SB];
    const int t = threadIdx.x;
    if (t < SB) s[t] = bsum[t];
    __syncthreads();
    if (t == 0) {
        int run = 0;
        for (int b = 0; b < SB; ++b) { int v = s[b]; s[b] = run; run += v; }
        row_ptr[0] = 0;
    }
    __syncthreads();
    if (t < SB) bsum[t] = s[t];
}

__global__ __launch_bounds__(256) void scan3_kernel(const int* __restrict__ cnt, const int* __restrict__ bsum,
                                                    int* __restrict__ row_ptr) {
    __shared__ int s[256];
    const int t = threadIdx.x;
    const int i = blockIdx.x * 256 + t;
    s[t] = (i < N_NODES) ? cnt[i] : 0;
    __syncthreads();
    if (t == 0) {
        int run = bsum[blockIdx.x];
        for (int j = 0; j < 256; ++j) { run += s[j]; s[j] = run; }
    }
    __syncthreads();
    if (i < N_NODES) row_ptr[i + 1] = s[t];
}

__global__ __launch_bounds__(256) void fill_kernel(const int* __restrict__ src, const int* __restrict__ dst,
                                                   int* __restrict__ cursor, int* __restrict__ col_idx) {
    int e = blockIdx.x * 256 + threadIdx.x;
    if (e < N_EDGES) {
        int d = dst[e];
        int slot = atomicAdd(&cursor[d], 1);
        col_idx[slot] = src[e];
    }
}

// sort each row's edge list ascending (selection sort on global; deg avg 4, max ~20).
// FP accumulation order is already nondeterministic (atomic fill), so reorder is benign.
__global__ __launch_bounds__(256) void sort_rows_kernel(const int* __restrict__ row_ptr, int* __restrict__ col_idx) {
    const int i = blockIdx.x * 256 + threadIdx.x;
    if (i >= N_NODES) return;
    const int s = row_ptr[i], e = row_ptr[i + 1];
    for (int a = s; a < e - 1; ++a) {
        int mi = a, mv = col_idx[a];
        for (int b = a + 1; b < e; ++b) {
            const int bv = col_idx[b];
            if (bv < mv) { mv = bv; mi = b; }
        }
        if (mi != a) { col_idx[mi] = col_idx[a]; col_idx[a] = mv; }
    }
}

// ---------------- weight pre-pack into MFMA B-fragment layout (bf16) ----------------
__global__ __launch_bounds__(256) void pack_w_kernel(const void* __restrict__ W1a, const void* __restrict__ W1b,
                                                     const void* __restrict__ W2, const int* __restrict__ mode,
                                                     u16* __restrict__ wpack) {
    const int t = blockIdx.x * 256 + threadIdx.x;  // 12*2048 = 24576
    if (t >= 24576) return;
    const int mat = t >> 11;
    const int r = t & 2047;
    const int l = r & 63;
    const int f = r >> 6;
    const int kb = f >> 3, nt = f & 7;
    const int k0 = kb * 32 + (l >> 4) * 8;
    const int n = nt * 16 + (l & 15);
    const int md = *mode;
    u16 vals[8];
    #pragma unroll
    for (int j = 0; j < 8; ++j) {
        const int k = k0 + j;
        float v;
        if (mat == 0) {
            v = (k < C_IN) ? (md ? ((const float*)W1a)[k * HD + n] : bf2f(((const u16*)W1a)[k * HD + n])) : 0.f;
        } else if (mat < 6) {
            const size_t o = (size_t)(mat - 1) * HD * HD + (size_t)k * HD + n;
            v = md ? ((const float*)W1b)[o] : bf2f(((const u16*)W1b)[o]);
        } else {
            const size_t o = (size_t)(mat - 6) * HD * HD + (size_t)k * HD + n;
            v = md ? ((const float*)W2)[o] : bf2f(((const u16*)W2)[o]);
        }
        vals[j] = f2bf(v);
    }
    uint4 o;
    o.x = (u32)vals[0] | ((u32)vals[1] << 16);
    o.y = (u32)vals[2] | ((u32)vals[3] << 16);
    o.z = (u32)vals[4] | ((u32)vals[5] << 16);
    o.w = (u32)vals[6] | ((u32)vals[7] << 16);
    *reinterpret_cast<uint4*>(wpack + (size_t)t * 8) = o;
}

// ---------------- bias pre-pack to f32 ----------------
__global__ __launch_bounds__(256) void pack_b_kernel(const void* __restrict__ b1, const void* __restrict__ b2,
                                                     const int* __restrict__ mode, float* __restrict__ biasf) {
    const int i = blockIdx.x * 256 + threadIdx.x;  // 12*128
    if (i >= 12 * HD) return;
    const int mat = i >> 7, c = i & 127;
    const int md = *mode;
    float v;
    if (mat < 6) v = md ? ((const float*)b1)[mat * HD + c] : bf2f(((const u16*)b1)[mat * HD + c]);
    else         v = md ? ((const float*)b2)[(mat - 6) * HD + c] : bf2f(((const u16*)b2)[(mat - 6) * HD + c]);
    biasf[i] = v;
}

// ---- shared helper: compute BN coef[256]={A,B} in LDS from replicated raw stats ----
__device__ __forceinline__ void coef_to_lds(float* coefs, const float* __restrict__ instats,
                                            const void* __restrict__ gammav, const void* __restrict__ betav,
                                            size_t gelem, int md, int tid) {
    if (tid < 128) {
        float sm = 0.f, sq = 0.f;
        #pragma unroll
        for (int rep = 0; rep < NREP; ++rep) {
            sm += instats[rep * 256 + tid];
            sq += instats[rep * 256 + 128 + tid];
        }
        const float inv_n = 1.0f / (float)N_NODES;
        const float mean = sm * inv_n;
        const float var = fmaxf(sq * inv_n - mean * mean, 0.f);
        const float rs = rsqrtf(var + BN_EPS);
        const float g  = md ? ((const float*)gammav)[gelem + tid] : bf2f(((const u16*)gammav)[gelem + tid]);
        const float be = md ? ((const float*)betav)[gelem + tid]  : bf2f(((const u16*)betav)[gelem + tid]);
        const float A = g * rs;
        coefs[tid] = A;
        coefs[128 + tid] = be - A * mean;
    }
}

// ---- shared 32-row MFMA + bias + store + stats epilogue (row-major out) ----
__device__ __forceinline__ void mfma_epilogue32(const u16 (*Asm)[136], const u16* __restrict__ wp,
                                                const float* __restrict__ biasf,
                                                float sred[2][128], float sqred[2][128],
                                                int m0, int tid, int bidx,
                                                u16* __restrict__ out, float* __restrict__ stats) {
    const int wave = tid >> 6, lane = tid & 63;
    const int quad = lane >> 4, lx = lane & 15;
    const int rowhalf = wave & 1;
    const int colhalf = wave >> 1;
    const int wrow = rowhalf * 16;
    f32x4 acc[4] = {};
    #pragma unroll
    for (int kb = 0; kb < 4; ++kb) {
        bf16x8 bfr[4];
        #pragma unroll
        for (int nt = 0; nt < 4; ++nt)
            bfr[nt] = *reinterpret_cast<const bf16x8*>(wp + (((size_t)(kb * 8 + colhalf * 4 + nt) * 64 + lane) << 3));
        const bf16x8 af = *reinterpret_cast<const bf16x8*>(&Asm[wrow + lx][kb * 32 + quad * 8]);
        #pragma unroll
        for (int nt = 0; nt < 4; ++nt)
            acc[nt] = __builtin_amdgcn_mfma_f32_16x16x32_bf16(af, bfr[nt], acc[nt], 0, 0, 0);
    }
    const int mrow0 = m0 + wrow;
    #pragma unroll
    for (int nt = 0; nt < 4; ++nt) {
        const int n = colhalf * 64 + nt * 16 + lx;
        const float bj = biasf[n];
        float s = 0.f, q = 0.f;
        #pragma unroll
        for (int r = 0; r < 4; ++r) {
            const int m = mrow0 + quad * 4 + r;
            const float v = acc[nt][r] + bj;
            out[(size_t)m * HD + n] = f2bf(v);
            s += v; q += v * v;
        }
        s += __shfl_xor(s, 16); s += __shfl_xor(s, 32);
        q += __shfl_xor(q, 16); q += __shfl_xor(q, 32);
        if (quad == 0) { sred[rowhalf][n] = s; sqred[rowhalf][n] = q; }
    }
    __syncthreads();
    float* sdst = stats + (size_t)(bidx & (NREP - 1)) * 256;
    if (tid < 128) {
        atomicAdd(&sdst[tid], sred[0][tid] + sred[1][tid]);
    } else {
        const int c2 = tid - 128;
        atomicAdd(&sdst[128 + c2], sqred[0][c2] + sqred[1][c2]);
    }
}

// ---------------- plain MFMA GEMM: BM=32 (3125 blocks), row-major, LDS A-stage ----------------
// TRANS: BN coefs computed in-block, applied while staging. IN-PLACE SAFE (out == A).
template <int TRANS, int STATS>
__global__ __launch_bounds__(256) void gemm_mfma(const u16* A, const u16* __restrict__ wp,
                                                 const float* __restrict__ biasf,
                                                 const float* __restrict__ instats,
                                                 const void* __restrict__ gammav, const void* __restrict__ betav,
                                                 size_t gelem, const int* __restrict__ mode,
                                                 u16* out, float* __restrict__ stats) {
    __shared__ u16 Asm[32][136];
    __shared__ float sred[2][128];
    __shared__ float sqred[2][128];
    __shared__ float coefs[256];
    const int tid = threadIdx.x;
    const int m0 = blockIdx.x * 32;
    const int rrow = tid >> 4;   // 0..15
    const int seg = tid & 15;

    if (TRANS) {
        coef_to_lds(coefs, instats, gammav, betav, gelem, *mode, tid);
        __syncthreads();
    }

    {
        float cA[8], cB[8];
        if (TRANS) {
            #pragma unroll
            for (int j = 0; j < 8; ++j) {
                cA[j] = coefs[seg * 8 + j];
                cB[j] = coefs[128 + seg * 8 + j];
            }
        }
        uint4 v[2];
        #pragma unroll
        for (int i = 0; i < 2; ++i) {
            const int gm = m0 + i * 16 + rrow;
            v[i] = *reinterpret_cast<const uint4*>(A + (size_t)gm * HD + seg * 8);
        }
        #pragma unroll
        for (int i = 0; i < 2; ++i) {
            uint4 o = v[i];
            if (TRANS) {
                u32 w[4] = {o.x, o.y, o.z, o.w};
                #pragma unroll
                for (int p = 0; p < 4; ++p) {
                    const float lo = lrelu(cA[2 * p] * bf2f_lo(w[p]) + cB[2 * p]);
                    const float hi = lrelu(cA[2 * p + 1] * bf2f_hi(w[p]) + cB[2 * p + 1]);
                    w[p] = pack2(lo, hi);
                }
                o.x = w[0]; o.y = w[1]; o.z = w[2]; o.w = w[3];
            }
            *reinterpret_cast<uint4*>(&Asm[i * 16 + rrow][seg * 8]) = o;
        }
    }
    __syncthreads();

    if (STATS) {
        mfma_epilogue32(Asm, wp, biasf, sred, sqred, m0, tid, blockIdx.x, out, stats);
    } else {
        const int wave = tid >> 6, lane = tid & 63;
        const int quad = lane >> 4, lx = lane & 15;
        const int rowhalf = wave & 1;
        const int colhalf = wave >> 1;
        const int wrow = rowhalf * 16;
        f32x4 acc[4] = {};
        #pragma unroll
        for (int kb = 0; kb < 4; ++kb) {
            bf16x8 bfr[4];
            #pragma unroll
            for (int nt = 0; nt < 4; ++nt)
                bfr[nt] = *reinterpret_cast<const bf16x8*>(wp + (((size_t)(kb * 8 + colhalf * 4 + nt) * 64 + lane) << 3));
            const bf16x8 af = *reinterpret_cast<const bf16x8*>(&Asm[wrow + lx][kb * 32 + quad * 8]);
            #pragma unroll
            for (int nt = 0; nt < 4; ++nt)
                acc[nt] = __builtin_amdgcn_mfma_f32_16x16x32_bf16(af, bfr[nt], acc[nt], 0, 0, 0);
        }
        const int mrow0 = m0 + wrow;
        #pragma unroll
        for (int nt = 0; nt < 4; ++nt) {
            const int n = colhalf * 64 + nt * 16 + lx;
            const float bj = biasf[n];
            #pragma unroll
            for (int r = 0; r < 4; ++r) {
                const int m = mrow0 + quad * 4 + r;
                out[(size_t)m * HD + n] = f2bf(acc[nt][r] + bj);
            }
        }
    }
}

// ---------------- SLICED gather+BN+lrelu + GEMM — BM=32 (3125 blocks) ----------------
// Edges per row are SORTED ascending; all blocks sweep 13 source-slices (2 MB each) in
// the same order with per-slice block barriers -> chip-wide working set per window is
// one slice -> random reads become L2 hits. Register accumulation; eidx via LDS.
__global__ __launch_bounds__(256) void gemm_gather(const u16* __restrict__ U, const int* __restrict__ row_ptr,
                                                   const int* __restrict__ col_idx,
                                                   const u16* __restrict__ wp,
                                                   const float* __restrict__ biasf,
                                                   const float* __restrict__ instats,
                                                   const void* __restrict__ gammav, const void* __restrict__ betav,
                                                   size_t gelem, const int* __restrict__ mode,
                                                   u16* __restrict__ out, float* __restrict__ stats) {
    __shared__ float coefs[256];
    __shared__ int rp[33];
    __shared__ int eidx[ECAP];
    __shared__ u16 Asm[32][136];
    __shared__ float sred[2][128];
    __shared__ float sqred[2][128];
    const int tid = threadIdx.x;
    const int m0 = blockIdx.x * 32;
    const int rrow = tid >> 4;   // 0..15
    const int seg = tid & 15;

    coef_to_lds(coefs, instats, gammav, betav, gelem, *mode, tid);
    if (tid < 33) rp[tid] = row_ptr[m0 + tid];
    __syncthreads();

    float cA[8], cB[8];
    #pragma unroll
    for (int j = 0; j < 8; ++j) {
        cA[j] = coefs[seg * 8 + j];
        cB[j] = coefs[128 + seg * 8 + j];
    }

    float a0[8], a1[8];
    #pragma unroll
    for (int j = 0; j < 8; ++j) { a0[j] = 0.f; a1[j] = 0.f; }
    // self rows (sequential reads)
    {
        const uint4 v0 = *reinterpret_cast<const uint4*>(U + (size_t)(m0 + rrow) * HD + seg * 8);
        const uint4 v1 = *reinterpret_cast<const uint4*>(U + (size_t)(m0 + 16 + rrow) * HD + seg * 8);
        acc_bn(a0, v0, cA, cB);
        acc_bn(a1, v1, cA, cB);
    }

    const int e0 = rp[0], e1 = rp[32];
    const int rs0 = rp[rrow], re0 = rp[rrow + 1];
    const int rs1 = rp[16 + rrow], re1 = rp[16 + rrow + 1];

    for (int base = e0; base < e1; base += ECAP) {
        const int n = min(ECAP, e1 - base);
        __syncthreads();
        for (int k = tid; k < n; k += 256) eidx[k] = col_idx[base + k];
        __syncthreads();
        int p0 = max(rs0, base), h0 = min(re0, base + n);
        int p1 = max(rs1, base), h1 = min(re1, base + n);
        int nxt0 = (p0 < h0) ? eidx[p0 - base] : 0x7fffffff;
        int nxt1 = (p1 < h1) ? eidx[p1 - base] : 0x7fffffff;
        for (int s = 1; s <= NSLICES; ++s) {
            const int send = s * SLICE;
            while (nxt0 < send) {
                const uint4 v = *reinterpret_cast<const uint4*>(U + (size_t)nxt0 * HD + seg * 8);
                acc_bn(a0, v, cA, cB);
                ++p0;
                nxt0 = (p0 < h0) ? eidx[p0 - base] : 0x7fffffff;
            }
            while (nxt1 < send) {
                const uint4 v = *reinterpret_cast<const uint4*>(U + (size_t)nxt1 * HD + seg * 8);
                acc_bn(a1, v, cA, cB);
                ++p1;
                nxt1 = (p1 < h1) ? eidx[p1 - base] : 0x7fffffff;
            }
            __syncthreads();   // keep the block's waves in the same slice window
        }
    }

    // pack to bf16 A-tile
    {
        uint4 o0, o1;
        o0.x = pack2(a0[0], a0[1]); o0.y = pack2(a0[2], a0[3]);
        o0.z = pack2(a0[4], a0[5]); o0.w = pack2(a0[6], a0[7]);
        o1.x = pack2(a1[0], a1[1]); o1.y = pack2(a1[2], a1[3]);
        o1.z = pack2(a1[4], a1[5]); o1.w = pack2(a1[6], a1[7]);
        *reinterpret_cast<uint4*>(&Asm[rrow][seg * 8]) = o0;
        *reinterpret_cast<uint4*>(&Asm[16 + rrow][seg * 8]) = o1;
    }
    __syncthreads();

    mfma_epilogue32(Asm, wp, biasf, sred, sqred, m0, tid, blockIdx.x, out, stats);
}

// ---------------- SLICED layer-0: gather over x (48 cols, no BN) + GEMM — BM=32 ----------------
__global__ __launch_bounds__(256) void gemm_gather0(const void* __restrict__ xv, const int* __restrict__ row_ptr,
                                                    const int* __restrict__ col_idx,
                                                    const u16* __restrict__ wp,
                                                    const float* __restrict__ biasf, const int* __restrict__ mode,
                                                    u16* __restrict__ out, float* __restrict__ stats) {
    __shared__ int rp[33];
    __shared__ int eidx[ECAP];
    __shared__ u16 Asm[32][136];
    __shared__ float sred[2][128];
    __shared__ float sqred[2][128];
    const int tid = threadIdx.x;
    const int m0 = blockIdx.x * 32;
    const int rrow = tid >> 4;
    const int seg = tid & 15;          // segs 0..5 carry data (48 cols), 6..15 zero
    const int md = *mode;
    const bool act = seg < 6;

    if (tid < 33) rp[tid] = row_ptr[m0 + tid];
    __syncthreads();

    float a0[8], a1[8];
    #pragma unroll
    for (int j = 0; j < 8; ++j) { a0[j] = 0.f; a1[j] = 0.f; }
    if (act) {
        ld_xrow(a0, xv, md, m0 + rrow, seg);
        ld_xrow(a1, xv, md, m0 + 16 + rrow, seg);
    }

    const int e0 = rp[0], e1 = rp[32];
    const int rs0 = rp[rrow], re0 = rp[rrow + 1];
    const int rs1 = rp[16 + rrow], re1 = rp[16 + rrow + 1];

    for (int base = e0; base < e1; base += ECAP) {
        const int n = min(ECAP, e1 - base);
        __syncthreads();
        for (int k = tid; k < n; k += 256) eidx[k] = col_idx[base + k];
        __syncthreads();
        int p0 = max(rs0, base), h0 = min(re0, base + n);
        int p1 = max(rs1, base), h1 = min(re1, base + n);
        if (!act) { p0 = h0; p1 = h1; }
        int nxt0 = (p0 < h0) ? eidx[p0 - base] : 0x7fffffff;
        int nxt1 = (p1 < h1) ? eidx[p1 - base] : 0x7fffffff;
        for (int s = 1; s <= NSLICES; ++s) {
            const int send = s * SLICE;
            while (nxt0 < send) {
                ld_xrow(a0, xv, md, nxt0, seg);
                ++p0;
                nxt0 = (p0 < h0) ? eidx[p0 - base] : 0x7fffffff;
            }
            while (nxt1 < send) {
                ld_xrow(a1, xv, md, nxt1, seg);
                ++p1;
                nxt1 = (p1 < h1) ? eidx[p1 - base] : 0x7fffffff;
            }
            __syncthreads();
        }
    }

    {
        uint4 o0, o1;
        if (act) {
            o0.x = pack2(a0[0], a0[1]); o0.y = pack2(a0[2], a0[3]);
            o0.z = pack2(a0[4], a0[5]); o0.w = pack2(a0[6], a0[7]);
            o1.x = pack2(a1[0], a1[1]); o1.y = pack2(a1[2], a1[3]);
            o1.z = pack2(a1[4], a1[5]); o1.w = pack2(a1[6], a1[7]);
        } else {
            o0.x = o0.y = o0.z = o0.w = 0;
            o1.x = o1.y = o1.z = o1.w = 0;
        }
        *reinterpret_cast<uint4*>(&Asm[rrow][seg * 8]) = o0;
        *reinterpret_cast<uint4*>(&Asm[16 + rrow][seg * 8]) = o1;
    }
    __syncthreads();

    mfma_epilogue32(Asm, wp, biasf, sred, sqred, m0, tid, blockIdx.x, out, stats);
}

// ---------------- pooling: wave per graph, uint4 row loads, quad-parallel rows ----------------
__global__ __launch_bounds__(256) void pool_kernel(const u16* __restrict__ hf, const int* __restrict__ batch,
                                                   const int* __restrict__ mode, float* __restrict__ emb,
                                                   void* __restrict__ outv) {
    const int wave = threadIdx.x >> 6, lane = threadIdx.x & 63;
    const int g = blockIdx.x * 4 + wave;
    if (g >= N_GRAPHS) return;
    const int md = *mode;
    const int quad = lane >> 4, c = lane & 15;
    int lo = 0, hi = N_NODES;
    while (lo < hi) { int m = (lo + hi) >> 1; if (batch[m] < g) lo = m + 1; else hi = m; }
    const int s = lo;
    hi = N_NODES;
    while (lo < hi) { int m = (lo + hi) >> 1; if (batch[m] < g + 1) lo = m + 1; else hi = m; }
    const int e = lo;
    const int cnt = e - s;
    float sum[8], mx[8];
    #pragma unroll
    for (int j = 0; j < 8; ++j) { sum[j] = 0.f; mx[j] = -INFINITY; }
    for (int n = s + quad; n < e; n += 4) {
        const uint4 v = *reinterpret_cast<const uint4*>(hf + (size_t)n * HD + c * 8);
        const u32 w[4] = {v.x, v.y, v.z, v.w};
        #pragma unroll
        for (int p = 0; p < 4; ++p) {
            const float f0 = bf2f_lo(w[p]), f1 = bf2f_hi(w[p]);
            sum[2 * p] += f0; sum[2 * p + 1] += f1;
            mx[2 * p] = fmaxf(mx[2 * p], f0); mx[2 * p + 1] = fmaxf(mx[2 * p + 1], f1);
        }
    }
    #pragma unroll
    for (int j = 0; j < 8; ++j) {
        sum[j] += __shfl_xor(sum[j], 16); sum[j] += __shfl_xor(sum[j], 32);
        mx[j] = fmaxf(mx[j], __shfl_xor(mx[j], 16));
        mx[j] = fmaxf(mx[j], __shfl_xor(mx[j], 32));
    }
    if (quad == 0) {
        const float invc = 1.0f / (float)max(cnt, 1);
        const size_t base = (size_t)N_GRAPHS * 3 + (size_t)g * 256;
        #pragma unroll
        for (int j = 0; j < 8; ++j) {
            const float mean = sum[j] * invc;
            const float m2 = (cnt == 0) ? 0.f : mx[j];
            const int col = c * 8 + j;
            emb[(size_t)g * 256 + col] = mean;
            emb[(size_t)g * 256 + 128 + col] = m2;
            if (md) {
                ((float*)outv)[base + col] = mean;
                ((float*)outv)[base + 128 + col] = m2;
            } else {
                ((u16*)outv)[base + col] = f2bf(mean);
                ((u16*)outv)[base + 128 + col] = f2bf(m2);
            }
        }
    }
}

__global__ __launch_bounds__(64) void final_kernel(const float* __restrict__ emb, const void* __restrict__ fcwv,
                                                   const void* __restrict__ fcbv, const void* __restrict__ fc2wv,
                                                   const void* __restrict__ fc2bv, const int* __restrict__ mode,
                                                   void* __restrict__ outv) {
    __shared__ float es[256];
    __shared__ float hs[64];
    const int g = blockIdx.x, t = threadIdx.x;
    const int md = *mode;
    reinterpret_cast<float4*>(es)[t] = reinterpret_cast<const float4*>(emb + (size_t)g * 256)[t];
    __syncthreads();
    float acc = md ? ((const float*)fcbv)[t] : bf2f(((const u16*)fcbv)[t]);
    if (md) {
        const float* w = (const float*)fcwv;
        #pragma unroll 8
        for (int k = 0; k < 256; ++k) acc += es[k] * w[k * 64 + t];
    } else {
        const u16* w = (const u16*)fcwv;
        #pragma unroll 8
        for (int k = 0; k < 256; ++k) acc += es[k] * bf2f(w[k * 64 + t]);
    }
    hs[t] = lrelu(acc);
    __syncthreads();
    if (t < 3) {
        float o = md ? ((const float*)fc2bv)[t] : bf2f(((const u16*)fc2bv)[t]);
        if (md) {
            const float* w = (const float*)fc2wv;
            #pragma unroll 8
            for (int j = 0; j < 64; ++j) o += hs[j] * w[j * 3 + t];
            ((float*)outv)[(size_t)g * 3 + t] = o;
        } else {
            const u16* w = (const u16*)fc2wv;
            #pragma unroll 8
            for (int j = 0; j < 64; ++j) o += hs[j] * bf2f(w[j * 3 + t]);
            ((u16*)outv)[(size_t)g * 3 + t] = f2bf(o);
        }
    }
}

// ---------------- launch ----------------
static inline size_t align256(size_t x) { return (x + 255) & ~(size_t)255; }

extern "C" void kernel_launch(void* const* d_in, const int* in_sizes, int n_in,
                              void* d_out, int out_size, void* d_ws, size_t ws_size,
                              hipStream_t stream) {
    (void)in_sizes; (void)n_in; (void)out_size; (void)ws_size;
    const void* x    = d_in[0];
    const void* W1a  = d_in[2];
    const void* W1b  = d_in[3];
    const void* b1   = d_in[4];
    const void* g1   = d_in[5];
    const void* be1  = d_in[6];
    const void* W2   = d_in[7];
    const void* b2   = d_in[8];
    const void* gn   = d_in[9];
    const void* bnb  = d_in[10];
    const void* fcw  = d_in[11];
    const void* fcb  = d_in[12];
    const void* fc2w = d_in[13];
    const void* fc2b = d_in[14];
    const int* ei    = (const int*)d_in[15];
    const int* batch = (const int*)d_in[16];

    char* p = (char*)d_ws;
    size_t off = 0;
    u16* zb = (u16*)(p + off); off += align256((size_t)N_NODES * HD * 2);
    u16* hb = (u16*)(p + off); off += align256((size_t)N_NODES * HD * 2);
    u16* wpack = (u16*)(p + off); off += align256((size_t)12 * HD * HD * 2);
    float* biasf = (float*)(p + off); off += align256((size_t)12 * HD * 4);
    float* emb = (float*)(p + off); off += align256((size_t)N_GRAPHS * 256 * 4);
    int* row_ptr = (int*)(p + off); off += align256((size_t)(N_NODES + 1) * 4);
    int* cursor = (int*)(p + off); off += align256((size_t)N_NODES * 4);
    int* col_idx = (int*)(p + off); off += align256((size_t)N_EDGES * 4);
    int* bsum = (int*)(p + off); off += align256((size_t)SB * 4);
    float* statsAll = (float*)(p + off); off += align256((size_t)12 * NREP * 256 * 4);
    int* mode = (int*)(p + off); off += align256(4);

    const int EB = (N_EDGES + 255) / 256;
    const int GB32 = N_NODES / 32;           // 3125 (BM=32, exact)

    detect_kernel<<<1, 256, 0, stream>>>((const u16*)x, mode);

    hipMemsetAsync(cursor, 0, (size_t)N_NODES * 4, stream);
    hipMemsetAsync(statsAll, 0, (size_t)12 * NREP * 256 * 4, stream);
    hist_kernel<<<EB, 256, 0, stream>>>(ei + N_EDGES, cursor);
    scan1_kernel<<<SB, 256, 0, stream>>>(cursor, bsum);
    scan2_kernel<<<1, 512, 0, stream>>>(bsum, row_ptr);
    scan3_kernel<<<SB, 256, 0, stream>>>(cursor, bsum, row_ptr);
    hipMemcpyAsync(cursor, row_ptr, (size_t)N_NODES * 4, hipMemcpyDeviceToDevice, stream);
    fill_kernel<<<EB, 256, 0, stream>>>(ei, ei + N_EDGES, cursor, col_idx);
    sort_rows_kernel<<<SB, 256, 0, stream>>>(row_ptr, col_idx);
    pack_w_kernel<<<96, 256, 0, stream>>>(W1a, W1b, W2, mode, wpack);
    pack_b_kernel<<<6, 256, 0, stream>>>(b1, b2, mode, biasf);

    u16* cur = zb;
    u16* oth = hb;
    for (int l = 0; l < NLAYERS; ++l) {
        float* statsA = statsAll + (size_t)l * NREP * 256;
        float* statsB = statsAll + (size_t)(6 + l) * NREP * 256;
        float* statsBprev = statsAll + (size_t)(6 + l - 1) * NREP * 256;
        if (l == 0) {
            // fused gather(x) + gemm1 (no BN on input): x -> cur
            gemm_gather0<<<GB32, 256, 0, stream>>>(x, row_ptr, col_idx, wpack,
                                                   biasf, mode, cur, statsA);
        } else {
            // fused gather+BN(outer,l-1)+lrelu + gemm1: cur -> oth
            gemm_gather<<<GB32, 256, 0, stream>>>(cur, row_ptr, col_idx,
                                                  wpack + (size_t)l * HD * HD,
                                                  biasf + (size_t)l * HD, statsBprev, gn, bnb,
                                                  (size_t)(l - 1) * HD, mode, oth, statsA);
            u16* t = cur; cur = oth; oth = t;
        }
        if (l < NLAYERS - 1) {
            gemm_mfma<1, 1><<<GB32, 256, 0, stream>>>(cur, wpack + (size_t)(6 + l) * HD * HD,
                                                      biasf + (size_t)(6 + l) * HD, statsA, g1, be1,
                                                      (size_t)l * HD, mode, cur, statsB);
        } else {
            gemm_mfma<1, 0><<<GB32, 256, 0, stream>>>(cur, wpack + (size_t)(6 + l) * HD * HD,
                                                      biasf + (size_t)(6 + l) * HD, statsA, g1, be1,
                                                      (size_t)l * HD, mode, cur, nullptr);
        }
    }

    pool_kernel<<<(N_GRAPHS + 3) / 4, 256, 0, stream>>>(cur, batch, mode, emb, d_out);
    final_kernel<<<N_GRAPHS, 64, 0, stream>>>(emb, fcw, fcb, fc2w, fc2b, mode, d_out);
}

// Round 6
// 477.989 us; speedup vs baseline: 1.3534x; 1.3534x over previous
//
#include <hip/hip_runtime.h>
#include <stdint.h>

#define N_NODES 100000
#define N_EDGES 400000
#define N_GRAPHS 2000
#define C_IN 48
#define HD 128
#define NLAYERS 6
#define BN_EPS 1e-5f
#define NSLOPE 0.01f
#define SB 391   // ceil(N_NODES/256)
#define NREP 8   // stats replication factor
#define DBINS 33 // degree buckets 0..31, 32 = clamp

typedef uint16_t u16;
typedef uint32_t u32;
typedef short bf16x8 __attribute__((ext_vector_type(8)));
typedef float f32x4 __attribute__((ext_vector_type(4)));

__device__ __forceinline__ float bf2f_lo(u32 v) { return __uint_as_float(v << 16); }
__device__ __forceinline__ float bf2f_hi(u32 v) { return __uint_as_float(v & 0xffff0000u); }
__device__ __forceinline__ float bf2f(u16 h) { return __uint_as_float(((u32)h) << 16); }
__device__ __forceinline__ u16 f2bf(float f) {
    u32 u = __float_as_uint(f);
    u32 r = (u + 0x7fffu + ((u >> 16) & 1u)) >> 16;
    return (u16)r;
}
__device__ __forceinline__ u32 pack2(float a, float b) {
    return (u32)f2bf(a) | ((u32)f2bf(b) << 16);
}
__device__ __forceinline__ float lrelu(float v) { return v >= 0.f ? v : v * NSLOPE; }

// register accumulate helpers
__device__ __forceinline__ void acc_bn(float* a, const uint4 v, const float* cA, const float* cB) {
    const u32 w[4] = {v.x, v.y, v.z, v.w};
    #pragma unroll
    for (int p = 0; p < 4; ++p) {
        a[2 * p]     += lrelu(cA[2 * p] * bf2f_lo(w[p]) + cB[2 * p]);
        a[2 * p + 1] += lrelu(cA[2 * p + 1] * bf2f_hi(w[p]) + cB[2 * p + 1]);
    }
}
__device__ __forceinline__ void acc_bf16row(float* a, const uint4 v) {
    const u32 w[4] = {v.x, v.y, v.z, v.w};
    #pragma unroll
    for (int p = 0; p < 4; ++p) {
        a[2 * p]     += bf2f_lo(w[p]);
        a[2 * p + 1] += bf2f_hi(w[p]);
    }
}
__device__ __forceinline__ void acc_f32row(float* a, const float* p) {
    const float4 u0 = reinterpret_cast<const float4*>(p)[0];
    const float4 u1 = reinterpret_cast<const float4*>(p)[1];
    a[0] += u0.x; a[1] += u0.y; a[2] += u0.z; a[3] += u0.w;
    a[4] += u1.x; a[5] += u1.y; a[6] += u1.z; a[7] += u1.w;
}
__device__ __forceinline__ void ld_xrow(float* a, const void* xv, int md, int idx, int seg) {
    if (md) acc_f32row(a, (const float*)xv + (size_t)idx * C_IN + seg * 8);
    else    acc_bf16row(a, *reinterpret_cast<const uint4*>((const u16*)xv + (size_t)idx * C_IN + seg * 8));
}

// dtype detection: mode=1 -> float inputs are fp32; mode=0 -> bf16.
__global__ __launch_bounds__(256) void detect_kernel(const u16* __restrict__ x, int* __restrict__ mode) {
    __shared__ int flag;
    if (threadIdx.x == 0) flag = 0;
    __syncthreads();
    int local = 0;
    for (int i = threadIdx.x; i < 16384; i += 256) {
        float a = fabsf(bf2f(x[i]));
        if (!(a < 1e4f)) local = 1;
    }
    if (local) flag = 1;
    __syncthreads();
    if (threadIdx.x == 0) mode[0] = flag;
}

// ---------------- CSR build ----------------
__global__ __launch_bounds__(256) void hist_kernel(const int* __restrict__ dst, int* __restrict__ cnt) {
    int e = blockIdx.x * 256 + threadIdx.x;
    if (e < N_EDGES) atomicAdd(&cnt[dst[e]], 1);
}

__global__ __launch_bounds__(256) void scan1_kernel(const int* __restrict__ cnt, int* __restrict__ bsum) {
    __shared__ int s[256];
    const int t = threadIdx.x;
    const int i = blockIdx.x * 256 + t;
    s[t] = (i < N_NODES) ? cnt[i] : 0;
    __syncthreads();
    for (int d = 128; d > 0; d >>= 1) {
        if (t < d) s[t] += s[t + d];
        __syncthreads();
    }
    if (t == 0) bsum[blockIdx.x] = s[0];
}

// parallel exclusive scan over SB block sums (Hillis-Steele)
__global__ __launch_bounds__(512) void scan2_kernel(int* __restrict__ bsum, int* __restrict__ row_ptr) {
    __shared__ int s[512];
    const int t = threadIdx.x;
    s[t] = (t < SB) ? bsum[t] : 0;
    __syncthreads();
    for (int d = 1; d < 512; d <<= 1) {
        const int v = (t >= d) ? s[t - d] : 0;
        __syncthreads();
        s[t] += v;
        __syncthreads();
    }
    if (t < SB) bsum[t] = (t == 0) ? 0 : s[t - 1];
    if (t == 0) row_ptr[0] = 0;
}

__global__ __launch_bounds__(256) void scan3_kernel(const int* __restrict__ cnt, const int* __restrict__ bsum,
                                                    int* __restrict__ row_ptr) {
    __shared__ int s[256];
    const int t = threadIdx.x;
    const int i = blockIdx.x * 256 + t;
    s[t] = (i < N_NODES) ? cnt[i] : 0;
    __syncthreads();
    if (t == 0) {
        int run = bsum[blockIdx.x];
        for (int j = 0; j < 256; ++j) { run += s[j]; s[j] = run; }
    }
    __syncthreads();
    if (i < N_NODES) row_ptr[i + 1] = s[t];
}

// fill stores PERMUTED source positions (pos[src]) for layers 1..5 and ORIGINAL ids for layer 0.
__global__ __launch_bounds__(256) void fill_kernel(const int* __restrict__ src, const int* __restrict__ dst,
                                                   const int* __restrict__ pos,
                                                   int* __restrict__ cursor, int* __restrict__ col_idx,
                                                   int* __restrict__ col0_idx) {
    int e = blockIdx.x * 256 + threadIdx.x;
    if (e < N_EDGES) {
        int d = dst[e];
        int slot = atomicAdd(&cursor[d], 1);
        const int sv = src[e];
        col_idx[slot] = pos[sv];
        col0_idx[slot] = sv;
    }
}

// ---------------- degree-balanced permutation (counting sort by degree, HEAVY-FIRST) ----------------
__global__ __launch_bounds__(256) void deg_hist_kernel(const int* __restrict__ row_ptr, int* __restrict__ dbins) {
    __shared__ int h[DBINS];
    const int tid = threadIdx.x;
    if (tid < DBINS) h[tid] = 0;
    __syncthreads();
    const int i = blockIdx.x * 256 + tid;
    if (i < N_NODES) atomicAdd(&h[min(row_ptr[i + 1] - row_ptr[i], 32)], 1);
    __syncthreads();
    if (tid < DBINS && h[tid]) atomicAdd(&dbins[tid], h[tid]);
}

// DESCENDING degree order: heavy blocks dispatch first (LPT scheduling)
__global__ __launch_bounds__(64) void deg_scan_kernel(int* __restrict__ dbins) {
    if (threadIdx.x == 0) {
        int run = 0;
        for (int b = DBINS - 1; b >= 0; --b) { int v = dbins[b]; dbins[b] = run; run += v; }
    }
}

__global__ __launch_bounds__(256) void deg_scatter_kernel(const int* __restrict__ row_ptr, int* __restrict__ dbins,
                                                          int* __restrict__ perm) {
    __shared__ int cnt[DBINS];
    __shared__ int base[DBINS];
    const int tid = threadIdx.x;
    const int i = blockIdx.x * 256 + tid;
    if (tid < DBINS) cnt[tid] = 0;
    __syncthreads();
    int d = 0, local = 0;
    const bool act = i < N_NODES;
    if (act) {
        d = min(row_ptr[i + 1] - row_ptr[i], 32);
        local = atomicAdd(&cnt[d], 1);
    }
    __syncthreads();
    if (tid < DBINS) base[tid] = cnt[tid] ? atomicAdd(&dbins[tid], cnt[tid]) : 0;
    __syncthreads();
    if (act) perm[base[d] + local] = i;
}

__global__ __launch_bounds__(256) void inv_kernel(const int* __restrict__ perm, int* __restrict__ pos) {
    const int i = blockIdx.x * 256 + threadIdx.x;
    if (i < N_NODES) pos[perm[i]] = i;
}

// ---------------- weight pre-pack into MFMA B-fragment layout (bf16) ----------------
__global__ __launch_bounds__(256) void pack_w_kernel(const void* __restrict__ W1a, const void* __restrict__ W1b,
                                                     const void* __restrict__ W2, const int* __restrict__ mode,
                                                     u16* __restrict__ wpack) {
    const int t = blockIdx.x * 256 + threadIdx.x;  // 12*2048 = 24576
    if (t >= 24576) return;
    const int mat = t >> 11;
    const int r = t & 2047;
    const int l = r & 63;
    const int f = r >> 6;
    const int kb = f >> 3, nt = f & 7;
    const int k0 = kb * 32 + (l >> 4) * 8;
    const int n = nt * 16 + (l & 15);
    const int md = *mode;
    u16 vals[8];
    #pragma unroll
    for (int j = 0; j < 8; ++j) {
        const int k = k0 + j;
        float v;
        if (mat == 0) {
            v = (k < C_IN) ? (md ? ((const float*)W1a)[k * HD + n] : bf2f(((const u16*)W1a)[k * HD + n])) : 0.f;
        } else if (mat < 6) {
            const size_t o = (size_t)(mat - 1) * HD * HD + (size_t)k * HD + n;
            v = md ? ((const float*)W1b)[o] : bf2f(((const u16*)W1b)[o]);
        } else {
            const size_t o = (size_t)(mat - 6) * HD * HD + (size_t)k * HD + n;
            v = md ? ((const float*)W2)[o] : bf2f(((const u16*)W2)[o]);
        }
        vals[j] = f2bf(v);
    }
    uint4 o;
    o.x = (u32)vals[0] | ((u32)vals[1] << 16);
    o.y = (u32)vals[2] | ((u32)vals[3] << 16);
    o.z = (u32)vals[4] | ((u32)vals[5] << 16);
    o.w = (u32)vals[6] | ((u32)vals[7] << 16);
    *reinterpret_cast<uint4*>(wpack + (size_t)t * 8) = o;
}

// ---------------- bias pre-pack to f32 ----------------
__global__ __launch_bounds__(256) void pack_b_kernel(const void* __restrict__ b1, const void* __restrict__ b2,
                                                     const int* __restrict__ mode, float* __restrict__ biasf) {
    const int i = blockIdx.x * 256 + threadIdx.x;  // 12*128
    if (i >= 12 * HD) return;
    const int mat = i >> 7, c = i & 127;
    const int md = *mode;
    float v;
    if (mat < 6) v = md ? ((const float*)b1)[mat * HD + c] : bf2f(((const u16*)b1)[mat * HD + c]);
    else         v = md ? ((const float*)b2)[(mat - 6) * HD + c] : bf2f(((const u16*)b2)[(mat - 6) * HD + c]);
    biasf[i] = v;
}

// ---- shared helper: compute BN coef[256]={A,B} in LDS from replicated raw stats ----
__device__ __forceinline__ void coef_to_lds(float* coefs, const float* __restrict__ instats,
                                            const void* __restrict__ gammav, const void* __restrict__ betav,
                                            size_t gelem, int md, int tid) {
    if (tid < 128) {
        float sm = 0.f, sq = 0.f;
        #pragma unroll
        for (int rep = 0; rep < NREP; ++rep) {
            sm += instats[rep * 256 + tid];
            sq += instats[rep * 256 + 128 + tid];
        }
        const float inv_n = 1.0f / (float)N_NODES;
        const float mean = sm * inv_n;
        const float var = fmaxf(sq * inv_n - mean * mean, 0.f);
        const float rs = rsqrtf(var + BN_EPS);
        const float g  = md ? ((const float*)gammav)[gelem + tid] : bf2f(((const u16*)gammav)[gelem + tid]);
        const float be = md ? ((const float*)betav)[gelem + tid]  : bf2f(((const u16*)betav)[gelem + tid]);
        const float A = g * rs;
        coefs[tid] = A;
        coefs[128 + tid] = be - A * mean;
    }
}

// ---- shared 32-row MFMA + bias + store + stats epilogue (permuted-space rows, exact grid) ----
__device__ __forceinline__ void mfma_epilogue32(const u16 (*Asm)[136], const u16* __restrict__ wp,
                                                const float* __restrict__ biasf,
                                                float sred[2][128], float sqred[2][128],
                                                int m0, int tid, int bidx,
                                                u16* __restrict__ out, float* __restrict__ stats) {
    const int wave = tid >> 6, lane = tid & 63;
    const int quad = lane >> 4, lx = lane & 15;
    const int rowhalf = wave & 1;
    const int colhalf = wave >> 1;
    const int wrow = rowhalf * 16;
    f32x4 acc[4] = {};
    #pragma unroll
    for (int kb = 0; kb < 4; ++kb) {
        bf16x8 bfr[4];
        #pragma unroll
        for (int nt = 0; nt < 4; ++nt)
            bfr[nt] = *reinterpret_cast<const bf16x8*>(wp + (((size_t)(kb * 8 + colhalf * 4 + nt) * 64 + lane) << 3));
        const bf16x8 af = *reinterpret_cast<const bf16x8*>(&Asm[wrow + lx][kb * 32 + quad * 8]);
        #pragma unroll
        for (int nt = 0; nt < 4; ++nt)
            acc[nt] = __builtin_amdgcn_mfma_f32_16x16x32_bf16(af, bfr[nt], acc[nt], 0, 0, 0);
    }
    const int mrow0 = m0 + wrow;
    #pragma unroll
    for (int nt = 0; nt < 4; ++nt) {
        const int n = colhalf * 64 + nt * 16 + lx;
        const float bj = biasf[n];
        float s = 0.f, q = 0.f;
        #pragma unroll
        for (int r = 0; r < 4; ++r) {
            const int m = mrow0 + quad * 4 + r;
            const float v = acc[nt][r] + bj;
            out[(size_t)m * HD + n] = f2bf(v);
            s += v; q += v * v;
        }
        s += __shfl_xor(s, 16); s += __shfl_xor(s, 32);
        q += __shfl_xor(q, 16); q += __shfl_xor(q, 32);
        if (quad == 0) { sred[rowhalf][n] = s; sqred[rowhalf][n] = q; }
    }
    __syncthreads();
    float* sdst = stats + (size_t)(bidx & (NREP - 1)) * 256;
    if (tid < 128) {
        atomicAdd(&sdst[tid], sred[0][tid] + sred[1][tid]);
    } else {
        const int c2 = tid - 128;
        atomicAdd(&sdst[128 + c2], sqred[0][c2] + sqred[1][c2]);
    }
}

// ---------------- plain MFMA GEMM: BM=32 (3125 blocks), LDS A-stage, permuted-space rows ----------------
// TRANS: BN coefs computed in-block, applied while staging. IN-PLACE SAFE (out == A).
template <int TRANS, int STATS>
__global__ __launch_bounds__(256) void gemm_mfma(const u16* A, const u16* __restrict__ wp,
                                                 const float* __restrict__ biasf,
                                                 const float* __restrict__ instats,
                                                 const void* __restrict__ gammav, const void* __restrict__ betav,
                                                 size_t gelem, const int* __restrict__ mode,
                                                 u16* out, float* __restrict__ stats) {
    __shared__ u16 Asm[32][136];
    __shared__ float sred[2][128];
    __shared__ float sqred[2][128];
    __shared__ float coefs[256];
    const int tid = threadIdx.x;
    const int m0 = blockIdx.x * 32;
    const int rrow = tid >> 4;   // 0..15
    const int seg = tid & 15;

    if (TRANS) {
        coef_to_lds(coefs, instats, gammav, betav, gelem, *mode, tid);
        __syncthreads();
    }

    {
        float cA[8], cB[8];
        if (TRANS) {
            #pragma unroll
            for (int j = 0; j < 8; ++j) {
                cA[j] = coefs[seg * 8 + j];
                cB[j] = coefs[128 + seg * 8 + j];
            }
        }
        uint4 v[2];
        #pragma unroll
        for (int i = 0; i < 2; ++i) {
            const int gm = m0 + i * 16 + rrow;
            v[i] = *reinterpret_cast<const uint4*>(A + (size_t)gm * HD + seg * 8);
        }
        #pragma unroll
        for (int i = 0; i < 2; ++i) {
            uint4 o = v[i];
            if (TRANS) {
                u32 w[4] = {o.x, o.y, o.z, o.w};
                #pragma unroll
                for (int p = 0; p < 4; ++p) {
                    const float lo = lrelu(cA[2 * p] * bf2f_lo(w[p]) + cB[2 * p]);
                    const float hi = lrelu(cA[2 * p + 1] * bf2f_hi(w[p]) + cB[2 * p + 1]);
                    w[p] = pack2(lo, hi);
                }
                o.x = w[0]; o.y = w[1]; o.z = w[2]; o.w = w[3];
            }
            *reinterpret_cast<uint4*>(&Asm[i * 16 + rrow][seg * 8]) = o;
        }
    }
    __syncthreads();

    if (STATS) {
        mfma_epilogue32(Asm, wp, biasf, sred, sqred, m0, tid, blockIdx.x, out, stats);
    } else {
        const int wave = tid >> 6, lane = tid & 63;
        const int quad = lane >> 4, lx = lane & 15;
        const int rowhalf = wave & 1;
        const int colhalf = wave >> 1;
        const int wrow = rowhalf * 16;
        f32x4 acc[4] = {};
        #pragma unroll
        for (int kb = 0; kb < 4; ++kb) {
            bf16x8 bfr[4];
            #pragma unroll
            for (int nt = 0; nt < 4; ++nt)
                bfr[nt] = *reinterpret_cast<const bf16x8*>(wp + (((size_t)(kb * 8 + colhalf * 4 + nt) * 64 + lane) << 3));
            const bf16x8 af = *reinterpret_cast<const bf16x8*>(&Asm[wrow + lx][kb * 32 + quad * 8]);
            #pragma unroll
            for (int nt = 0; nt < 4; ++nt)
                acc[nt] = __builtin_amdgcn_mfma_f32_16x16x32_bf16(af, bfr[nt], acc[nt], 0, 0, 0);
        }
        const int mrow0 = m0 + wrow;
        #pragma unroll
        for (int nt = 0; nt < 4; ++nt) {
            const int n = colhalf * 64 + nt * 16 + lx;
            const float bj = biasf[n];
            #pragma unroll
            for (int r = 0; r < 4; ++r) {
                const int m = mrow0 + quad * 4 + r;
                out[(size_t)m * HD + n] = f2bf(acc[nt][r] + bj);
            }
        }
    }
}

// ---------------- FUSED gather+BN+lrelu GEMM — BM=32 (3125 blocks), 2 chains/thread, 4-wide ----------------
// Tables live in PERMUTED layout: row i of U/out is node perm[i]. Self reads and all
// writes are sequential; neighbor indices (col2) are pre-remapped to permuted positions.
// row_ptr is indexed by ORIGINAL node id (perm[lm]). NOT in-place. STATS on.
__global__ __launch_bounds__(256) void gemm_gather(const u16* __restrict__ U, const int* __restrict__ row_ptr,
                                                   const int* __restrict__ col2, const int* __restrict__ perm,
                                                   const u16* __restrict__ wp,
                                                   const float* __restrict__ biasf,
                                                   const float* __restrict__ instats,
                                                   const void* __restrict__ gammav, const void* __restrict__ betav,
                                                   size_t gelem, const int* __restrict__ mode,
                                                   u16* __restrict__ out, float* __restrict__ stats) {
    __shared__ u16 Asm[32][136];
    __shared__ float sred[2][128];
    __shared__ float sqred[2][128];
    __shared__ float coefs[256];
    const int tid = threadIdx.x;
    const int m0 = blockIdx.x * 32;
    const int rrow = tid >> 4;   // 0..15
    const int seg = tid & 15;

    coef_to_lds(coefs, instats, gammav, betav, gelem, *mode, tid);
    __syncthreads();

    {
        float cA[8], cB[8];
        #pragma unroll
        for (int j = 0; j < 8; ++j) {
            cA[j] = coefs[seg * 8 + j];
            cB[j] = coefs[128 + seg * 8 + j];
        }
        const int lm0 = m0 + rrow;          // N_NODES % 32 == 0: always valid
        const int lm1 = m0 + 16 + rrow;
        const int gm0 = perm[lm0];
        const int gm1 = perm[lm1];
        float a0[8], a1[8];
        #pragma unroll
        for (int j = 0; j < 8; ++j) { a0[j] = 0.f; a1[j] = 0.f; }
        // self rows: sequential in permuted table
        const uint4 v0 = *reinterpret_cast<const uint4*>(U + (size_t)lm0 * HD + seg * 8);
        const uint4 v1 = *reinterpret_cast<const uint4*>(U + (size_t)lm1 * HD + seg * 8);
        acc_bn(a0, v0, cA, cB);
        acc_bn(a1, v1, cA, cB);
        const int s0 = row_ptr[gm0], d0 = row_ptr[gm0 + 1] - s0;
        const int s1 = row_ptr[gm1], d1 = row_ptr[gm1 + 1] - s1;
        const int dm = max(d0, d1);
        for (int t = 0; t < dm; t += 4) {
            const bool p00 = t < d0, p01 = (t + 1) < d0, p02 = (t + 2) < d0, p03 = (t + 3) < d0;
            const bool p10 = t < d1, p11 = (t + 1) < d1, p12 = (t + 2) < d1, p13 = (t + 3) < d1;
            int i00 = 0, i01 = 0, i02 = 0, i03 = 0;
            int i10 = 0, i11 = 0, i12 = 0, i13 = 0;
            if (p00) i00 = col2[s0 + t];
            if (p01) i01 = col2[s0 + t + 1];
            if (p02) i02 = col2[s0 + t + 2];
            if (p03) i03 = col2[s0 + t + 3];
            if (p10) i10 = col2[s1 + t];
            if (p11) i11 = col2[s1 + t + 1];
            if (p12) i12 = col2[s1 + t + 2];
            if (p13) i13 = col2[s1 + t + 3];
            uint4 r00{}, r01{}, r02{}, r03{}, r10{}, r11{}, r12{}, r13{};
            if (p00) r00 = *reinterpret_cast<const uint4*>(U + (size_t)i00 * HD + seg * 8);
            if (p01) r01 = *reinterpret_cast<const uint4*>(U + (size_t)i01 * HD + seg * 8);
            if (p02) r02 = *reinterpret_cast<const uint4*>(U + (size_t)i02 * HD + seg * 8);
            if (p03) r03 = *reinterpret_cast<const uint4*>(U + (size_t)i03 * HD + seg * 8);
            if (p10) r10 = *reinterpret_cast<const uint4*>(U + (size_t)i10 * HD + seg * 8);
            if (p11) r11 = *reinterpret_cast<const uint4*>(U + (size_t)i11 * HD + seg * 8);
            if (p12) r12 = *reinterpret_cast<const uint4*>(U + (size_t)i12 * HD + seg * 8);
            if (p13) r13 = *reinterpret_cast<const uint4*>(U + (size_t)i13 * HD + seg * 8);
            if (p00) acc_bn(a0, r00, cA, cB);
            if (p01) acc_bn(a0, r01, cA, cB);
            if (p02) acc_bn(a0, r02, cA, cB);
            if (p03) acc_bn(a0, r03, cA, cB);
            if (p10) acc_bn(a1, r10, cA, cB);
            if (p11) acc_bn(a1, r11, cA, cB);
            if (p12) acc_bn(a1, r12, cA, cB);
            if (p13) acc_bn(a1, r13, cA, cB);
        }
        uint4 o0, o1;
        o0.x = pack2(a0[0], a0[1]); o0.y = pack2(a0[2], a0[3]);
        o0.z = pack2(a0[4], a0[5]); o0.w = pack2(a0[6], a0[7]);
        o1.x = pack2(a1[0], a1[1]); o1.y = pack2(a1[2], a1[3]);
        o1.z = pack2(a1[4], a1[5]); o1.w = pack2(a1[6], a1[7]);
        *reinterpret_cast<uint4*>(&Asm[rrow][seg * 8]) = o0;
        *reinterpret_cast<uint4*>(&Asm[16 + rrow][seg * 8]) = o1;
    }
    __syncthreads();

    mfma_epilogue32(Asm, wp, biasf, sred, sqred, m0, tid, blockIdx.x, out, stats);
}

// ---------------- FUSED layer-0: gather over x (original layout, col0 ids) + GEMM — BM=32 ----------------
// x rows read at ORIGINAL ids; col0 holds original src ids (no perm indirection).
// Writes out in PERMUTED layout (sequential).
__global__ __launch_bounds__(256) void gemm_gather0(const void* __restrict__ xv, const int* __restrict__ row_ptr,
                                                    const int* __restrict__ col0, const int* __restrict__ perm,
                                                    const u16* __restrict__ wp,
                                                    const float* __restrict__ biasf, const int* __restrict__ mode,
                                                    u16* __restrict__ out, float* __restrict__ stats) {
    __shared__ u16 Asm[32][136];
    __shared__ float sred[2][128];
    __shared__ float sqred[2][128];
    const int tid = threadIdx.x;
    const int m0 = blockIdx.x * 32;
    const int rrow = tid >> 4;
    const int seg = tid & 15;          // segs 0..5 carry data (48 cols), 6..15 zero
    const int md = *mode;
    const bool act = seg < 6;

    {
        const int lm0 = m0 + rrow;
        const int lm1 = m0 + 16 + rrow;
        const int gm0 = perm[lm0];
        const int gm1 = perm[lm1];
        float a0[8], a1[8];
        #pragma unroll
        for (int j = 0; j < 8; ++j) { a0[j] = 0.f; a1[j] = 0.f; }
        const int s0 = row_ptr[gm0], d0 = row_ptr[gm0 + 1] - s0;
        const int s1 = row_ptr[gm1], d1 = row_ptr[gm1 + 1] - s1;
        if (act) {
            ld_xrow(a0, xv, md, gm0, seg);
            ld_xrow(a1, xv, md, gm1, seg);
            const int dm = max(d0, d1);
            for (int t = 0; t < dm; t += 4) {
                const bool p00 = t < d0, p01 = (t + 1) < d0, p02 = (t + 2) < d0, p03 = (t + 3) < d0;
                const bool p10 = t < d1, p11 = (t + 1) < d1, p12 = (t + 2) < d1, p13 = (t + 3) < d1;
                int i00 = 0, i01 = 0, i02 = 0, i03 = 0;
                int i10 = 0, i11 = 0, i12 = 0, i13 = 0;
                if (p00) i00 = col0[s0 + t];
                if (p01) i01 = col0[s0 + t + 1];
                if (p02) i02 = col0[s0 + t + 2];
                if (p03) i03 = col0[s0 + t + 3];
                if (p10) i10 = col0[s1 + t];
                if (p11) i11 = col0[s1 + t + 1];
                if (p12) i12 = col0[s1 + t + 2];
                if (p13) i13 = col0[s1 + t + 3];
                if (p00) ld_xrow(a0, xv, md, i00, seg);
                if (p01) ld_xrow(a0, xv, md, i01, seg);
                if (p02) ld_xrow(a0, xv, md, i02, seg);
                if (p03) ld_xrow(a0, xv, md, i03, seg);
                if (p10) ld_xrow(a1, xv, md, i10, seg);
                if (p11) ld_xrow(a1, xv, md, i11, seg);
                if (p12) ld_xrow(a1, xv, md, i12, seg);
                if (p13) ld_xrow(a1, xv, md, i13, seg);
            }
        }
        uint4 o0, o1;
        o0.x = pack2(a0[0], a0[1]); o0.y = pack2(a0[2], a0[3]);
        o0.z = pack2(a0[4], a0[5]); o0.w = pack2(a0[6], a0[7]);
        o1.x = pack2(a1[0], a1[1]); o1.y = pack2(a1[2], a1[3]);
        o1.z = pack2(a1[4], a1[5]); o1.w = pack2(a1[6], a1[7]);
        *reinterpret_cast<uint4*>(&Asm[rrow][seg * 8]) = o0;
        *reinterpret_cast<uint4*>(&Asm[16 + rrow][seg * 8]) = o1;
    }
    __syncthreads();

    mfma_epilogue32(Asm, wp, biasf, sred, sqred, m0, tid, blockIdx.x, out, stats);
}

// ---------------- pooling: wave per graph, pos-indirection into permuted table ----------------
__global__ __launch_bounds__(256) void pool_kernel(const u16* __restrict__ hf, const int* __restrict__ batch,
                                                   const int* __restrict__ pos,
                                                   const int* __restrict__ mode, float* __restrict__ emb,
                                                   void* __restrict__ outv) {
    const int wave = threadIdx.x >> 6, lane = threadIdx.x & 63;
    const int g = blockIdx.x * 4 + wave;
    if (g >= N_GRAPHS) return;
    const int md = *mode;
    const int quad = lane >> 4, c = lane & 15;
    int lo = 0, hi = N_NODES;
    while (lo < hi) { int m = (lo + hi) >> 1; if (batch[m] < g) lo = m + 1; else hi = m; }
    const int s = lo;
    hi = N_NODES;
    while (lo < hi) { int m = (lo + hi) >> 1; if (batch[m] < g + 1) lo = m + 1; else hi = m; }
    const int e = lo;
    const int cnt = e - s;
    float sum[8], mx[8];
    #pragma unroll
    for (int j = 0; j < 8; ++j) { sum[j] = 0.f; mx[j] = -INFINITY; }
    for (int n = s + quad; n < e; n += 4) {
        const int p = pos[n];
        const uint4 v = *reinterpret_cast<const uint4*>(hf + (size_t)p * HD + c * 8);
        const u32 w[4] = {v.x, v.y, v.z, v.w};
        #pragma unroll
        for (int pp = 0; pp < 4; ++pp) {
            const float f0 = bf2f_lo(w[pp]), f1 = bf2f_hi(w[pp]);
            sum[2 * pp] += f0; sum[2 * pp + 1] += f1;
            mx[2 * pp] = fmaxf(mx[2 * pp], f0); mx[2 * pp + 1] = fmaxf(mx[2 * pp + 1], f1);
        }
    }
    #pragma unroll
    for (int j = 0; j < 8; ++j) {
        sum[j] += __shfl_xor(sum[j], 16); sum[j] += __shfl_xor(sum[j], 32);
        mx[j] = fmaxf(mx[j], __shfl_xor(mx[j], 16));
        mx[j] = fmaxf(mx[j], __shfl_xor(mx[j], 32));
    }
    if (quad == 0) {
        const float invc = 1.0f / (float)max(cnt, 1);
        const size_t base = (size_t)N_GRAPHS * 3 + (size_t)g * 256;
        #pragma unroll
        for (int j = 0; j < 8; ++j) {
            const float mean = sum[j] * invc;
            const float m2 = (cnt == 0) ? 0.f : mx[j];
            const int col = c * 8 + j;
            emb[(size_t)g * 256 + col] = mean;
            emb[(size_t)g * 256 + 128 + col] = m2;
            if (md) {
                ((float*)outv)[base + col] = mean;
                ((float*)outv)[base + 128 + col] = m2;
            } else {
                ((u16*)outv)[base + col] = f2bf(mean);
                ((u16*)outv)[base + 128 + col] = f2bf(m2);
            }
        }
    }
}

__global__ __launch_bounds__(64) void final_kernel(const float* __restrict__ emb, const void* __restrict__ fcwv,
                                                   const void* __restrict__ fcbv, const void* __restrict__ fc2wv,
                                                   const void* __restrict__ fc2bv, const int* __restrict__ mode,
                                                   void* __restrict__ outv) {
    __shared__ float es[256];
    __shared__ float hs[64];
    const int g = blockIdx.x, t = threadIdx.x;
    const int md = *mode;
    reinterpret_cast<float4*>(es)[t] = reinterpret_cast<const float4*>(emb + (size_t)g * 256)[t];
    __syncthreads();
    float acc = md ? ((const float*)fcbv)[t] : bf2f(((const u16*)fcbv)[t]);
    if (md) {
        const float* w = (const float*)fcwv;
        #pragma unroll 8
        for (int k = 0; k < 256; ++k) acc += es[k] * w[k * 64 + t];
    } else {
        const u16* w = (const u16*)fcwv;
        #pragma unroll 8
        for (int k = 0; k < 256; ++k) acc += es[k] * bf2f(w[k * 64 + t]);
    }
    hs[t] = lrelu(acc);
    __syncthreads();
    if (t < 3) {
        float o = md ? ((const float*)fc2bv)[t] : bf2f(((const u16*)fc2bv)[t]);
        if (md) {
            const float* w = (const float*)fc2wv;
            #pragma unroll 8
            for (int j = 0; j < 64; ++j) o += hs[j] * w[j * 3 + t];
            ((float*)outv)[(size_t)g * 3 + t] = o;
        } else {
            const u16* w = (const u16*)fc2wv;
            #pragma unroll 8
            for (int j = 0; j < 64; ++j) o += hs[j] * bf2f(w[j * 3 + t]);
            ((u16*)outv)[(size_t)g * 3 + t] = f2bf(o);
        }
    }
}

// ---------------- launch ----------------
static inline size_t align256(size_t x) { return (x + 255) & ~(size_t)255; }

extern "C" void kernel_launch(void* const* d_in, const int* in_sizes, int n_in,
                              void* d_out, int out_size, void* d_ws, size_t ws_size,
                              hipStream_t stream) {
    (void)in_sizes; (void)n_in; (void)out_size; (void)ws_size;
    const void* x    = d_in[0];
    const void* W1a  = d_in[2];
    const void* W1b  = d_in[3];
    const void* b1   = d_in[4];
    const void* g1   = d_in[5];
    const void* be1  = d_in[6];
    const void* W2   = d_in[7];
    const void* b2   = d_in[8];
    const void* gn   = d_in[9];
    const void* bnb  = d_in[10];
    const void* fcw  = d_in[11];
    const void* fcb  = d_in[12];
    const void* fc2w = d_in[13];
    const void* fc2b = d_in[14];
    const int* ei    = (const int*)d_in[15];
    const int* batch = (const int*)d_in[16];

    char* p = (char*)d_ws;
    size_t off = 0;
    u16* zb = (u16*)(p + off); off += align256((size_t)N_NODES * HD * 2);
    u16* hb = (u16*)(p + off); off += align256((size_t)N_NODES * HD * 2);
    u16* wpack = (u16*)(p + off); off += align256((size_t)12 * HD * HD * 2);
    float* biasf = (float*)(p + off); off += align256((size_t)12 * HD * 4);
    float* emb = (float*)(p + off); off += align256((size_t)N_GRAPHS * 256 * 4);
    int* row_ptr = (int*)(p + off); off += align256((size_t)(N_NODES + 1) * 4);
    int* cursor = (int*)(p + off); off += align256((size_t)N_NODES * 4);
    int* col_idx = (int*)(p + off); off += align256((size_t)N_EDGES * 4);
    int* col0_idx = (int*)(p + off); off += align256((size_t)N_EDGES * 4);
    int* bsum = (int*)(p + off); off += align256((size_t)SB * 4);
    float* statsAll = (float*)(p + off); off += align256((size_t)12 * NREP * 256 * 4);
    int* perm = (int*)(p + off); off += align256((size_t)N_NODES * 4);
    int* pos = (int*)(p + off); off += align256((size_t)N_NODES * 4);
    int* dbins = (int*)(p + off); off += align256((size_t)64 * 4);
    int* mode = (int*)(p + off); off += align256(4);

    const int EB = (N_EDGES + 255) / 256;
    const int GB32 = N_NODES / 32;           // 3125 (BM=32, exact)

    detect_kernel<<<1, 256, 0, stream>>>((const u16*)x, mode);

    hipMemsetAsync(cursor, 0, (size_t)N_NODES * 4, stream);
    hipMemsetAsync(statsAll, 0, (size_t)12 * NREP * 256 * 4, stream);
    hipMemsetAsync(dbins, 0, (size_t)DBINS * 4, stream);
    hist_kernel<<<EB, 256, 0, stream>>>(ei + N_EDGES, cursor);
    scan1_kernel<<<SB, 256, 0, stream>>>(cursor, bsum);
    scan2_kernel<<<1, 512, 0, stream>>>(bsum, row_ptr);
    scan3_kernel<<<SB, 256, 0, stream>>>(cursor, bsum, row_ptr);
    // degree-balanced permutation, heavy-first (needs completed row_ptr)
    deg_hist_kernel<<<SB, 256, 0, stream>>>(row_ptr, dbins);
    deg_scan_kernel<<<1, 64, 0, stream>>>(dbins);
    deg_scatter_kernel<<<SB, 256, 0, stream>>>(row_ptr, dbins, perm);
    inv_kernel<<<SB, 256, 0, stream>>>(perm, pos);
    hipMemcpyAsync(cursor, row_ptr, (size_t)N_NODES * 4, hipMemcpyDeviceToDevice, stream);
    fill_kernel<<<EB, 256, 0, stream>>>(ei, ei + N_EDGES, pos, cursor, col_idx, col0_idx);
    pack_w_kernel<<<96, 256, 0, stream>>>(W1a, W1b, W2, mode, wpack);
    pack_b_kernel<<<6, 256, 0, stream>>>(b1, b2, mode, biasf);

    u16* cur = zb;
    u16* oth = hb;
    for (int l = 0; l < NLAYERS; ++l) {
        float* statsA = statsAll + (size_t)l * NREP * 256;
        float* statsB = statsAll + (size_t)(6 + l) * NREP * 256;
        float* statsBprev = statsAll + (size_t)(6 + l - 1) * NREP * 256;
        if (l == 0) {
            // fused gather(x) + gemm1 (no BN on input): x (original) -> cur (permuted)
            gemm_gather0<<<GB32, 256, 0, stream>>>(x, row_ptr, col0_idx, perm, wpack,
                                                   biasf, mode, cur, statsA);
        } else {
            // fused gather+BN(outer,l-1)+lrelu + gemm1: cur -> oth (permuted space)
            gemm_gather<<<GB32, 256, 0, stream>>>(cur, row_ptr, col_idx, perm,
                                                  wpack + (size_t)l * HD * HD,
                                                  biasf + (size_t)l * HD, statsBprev, gn, bnb,
                                                  (size_t)(l - 1) * HD, mode, oth, statsA);
            u16* t = cur; cur = oth; oth = t;
        }
        if (l < NLAYERS - 1) {
            gemm_mfma<1, 1><<<GB32, 256, 0, stream>>>(cur, wpack + (size_t)(6 + l) * HD * HD,
                                                      biasf + (size_t)(6 + l) * HD, statsA, g1, be1,
                                                      (size_t)l * HD, mode, cur, statsB);
        } else {
            gemm_mfma<1, 0><<<GB32, 256, 0, stream>>>(cur, wpack + (size_t)(6 + l) * HD * HD,
                                                      biasf + (size_t)(6 + l) * HD, statsA, g1, be1,
                                                      (size_t)l * HD, mode, cur, nullptr);
        }
    }

    pool_kernel<<<(N_GRAPHS + 3) / 4, 256, 0, stream>>>(cur, batch, pos, mode, emb, d_out);
    final_kernel<<<N_GRAPHS, 64, 0, stream>>>(emb, fcw, fcb, fc2w, fc2b, mode, d_out);
}